// Round 2
// baseline (243193.848 us; speedup 1.0000x reference)
//
#include <hip/hip_runtime.h>
#include <math.h>

#define BATCH  65536
#define SD     256      // STATE_DIM
#define AD     129      // ACTION_DIM
#define HID    256
#define NSTEP  30
#define EPS_LN 1e-5f

#define RPB    16       // rows per block (4 waves x 4 rows/wave)
#define G      16       // lanes per row; each lane owns 16 hidden cols
#define HSTR   260      // h_lds row stride (dwords)
#define XSTR   132      // x_lds row stride (dwords); [129]=t, K=130
#define W3STR  132      // padded W3 stride in d_ws

// Repack W3 (256x129 row-major) -> W3p (256x132, zero-padded), aligned float4 cols.
__global__ __launch_bounds__(256)
void repack_w3(const float* __restrict__ W3, float* __restrict__ W3p) {
    int idx = blockIdx.x * 256 + threadIdx.x;
    if (idx < HID * W3STR) {
        int k = idx / W3STR;
        int j = idx - k * W3STR;
        W3p[idx] = (j < AD) ? W3[k * AD + j] : 0.0f;
    }
}

__device__ __forceinline__ float4 ldf4(const float* p) { return *(const float4*)p; }

#define FMA16(h, w0, w1, w2, w3, A)                                         \
    A[0]  = fmaf(h, w0.x, A[0]);  A[1]  = fmaf(h, w0.y, A[1]);              \
    A[2]  = fmaf(h, w0.z, A[2]);  A[3]  = fmaf(h, w0.w, A[3]);              \
    A[4]  = fmaf(h, w1.x, A[4]);  A[5]  = fmaf(h, w1.y, A[5]);              \
    A[6]  = fmaf(h, w1.z, A[6]);  A[7]  = fmaf(h, w1.w, A[7]);              \
    A[8]  = fmaf(h, w2.x, A[8]);  A[9]  = fmaf(h, w2.y, A[9]);              \
    A[10] = fmaf(h, w2.z, A[10]); A[11] = fmaf(h, w2.w, A[11]);             \
    A[12] = fmaf(h, w3.x, A[12]); A[13] = fmaf(h, w3.y, A[13]);             \
    A[14] = fmaf(h, w3.z, A[14]); A[15] = fmaf(h, w3.w, A[15]);

#define FMA8(h, w0, w1, A)                                                  \
    A[0] = fmaf(h, w0.x, A[0]);  A[1] = fmaf(h, w0.y, A[1]);                \
    A[2] = fmaf(h, w0.z, A[2]);  A[3] = fmaf(h, w0.w, A[3]);                \
    A[4] = fmaf(h, w1.x, A[4]);  A[5] = fmaf(h, w1.y, A[5]);                \
    A[6] = fmaf(h, w1.z, A[6]);  A[7] = fmaf(h, w1.w, A[7]);

// A[16] += sum_k in[k] * W[k*ldw + (col base folded into Wb)], distance-2 pipeline.
// K must be even, >= 4.
__device__ __forceinline__ void mac16(const float* __restrict__ Wb, int ldw,
                                      const float* __restrict__ in, int K,
                                      float* __restrict__ A)
{
    float4 a0 = ldf4(Wb),     a1 = ldf4(Wb + 4),
           a2 = ldf4(Wb + 8), a3 = ldf4(Wb + 12);
    const float* p1 = Wb + ldw;
    float4 b0 = ldf4(p1),     b1 = ldf4(p1 + 4),
           b2 = ldf4(p1 + 8), b3 = ldf4(p1 + 12);
    #pragma unroll 1
    for (int k = 0; k < K; k += 2) {
        const float* p2 = Wb + (size_t)((k + 2 < K) ? k + 2 : K - 2) * ldw;
        const float* p3 = Wb + (size_t)((k + 3 < K) ? k + 3 : K - 1) * ldw;
        float4 n0 = ldf4(p2), n1 = ldf4(p2 + 4), n2 = ldf4(p2 + 8), n3 = ldf4(p2 + 12);
        float4 m0 = ldf4(p3), m1 = ldf4(p3 + 4), m2 = ldf4(p3 + 8), m3 = ldf4(p3 + 12);
        float h0 = in[k];
        float h1 = in[k + 1];
        FMA16(h0, a0, a1, a2, a3, A);
        FMA16(h1, b0, b1, b2, b3, A);
        a0 = n0; a1 = n1; a2 = n2; a3 = n3;
        b0 = m0; b1 = m1; b2 = m2; b3 = m3;
    }
}

__device__ __forceinline__ void mac8(const float* __restrict__ Wb, int ldw,
                                     const float* __restrict__ in, int K,
                                     float* __restrict__ A)
{
    float4 a0 = ldf4(Wb), a1 = ldf4(Wb + 4);
    const float* p1 = Wb + ldw;
    float4 b0 = ldf4(p1), b1 = ldf4(p1 + 4);
    #pragma unroll 1
    for (int k = 0; k < K; k += 2) {
        const float* p2 = Wb + (size_t)((k + 2 < K) ? k + 2 : K - 2) * ldw;
        const float* p3 = Wb + (size_t)((k + 3 < K) ? k + 3 : K - 1) * ldw;
        float4 n0 = ldf4(p2), n1 = ldf4(p2 + 4);
        float4 m0 = ldf4(p3), m1 = ldf4(p3 + 4);
        float h0 = in[k];
        float h1 = in[k + 1];
        FMA8(h0, a0, a1, A);
        FMA8(h1, b0, b1, A);
        a0 = n0; a1 = n1;
        b0 = m0; b1 = m1;
    }
}

__global__ __launch_bounds__(256, 3)
void actor_kernel(const float* __restrict__ state,
                  const float* __restrict__ amask,
                  const float* __restrict__ x_init,
                  const float* __restrict__ gum,
                  const float* __restrict__ W1,
                  const float* __restrict__ b1,
                  const float* __restrict__ g1,
                  const float* __restrict__ be1,
                  const float* __restrict__ W2,
                  const float* __restrict__ b2,
                  const float* __restrict__ g2,
                  const float* __restrict__ be2,
                  const float* __restrict__ W3p,
                  const float* __restrict__ b3,
                  float* __restrict__ out)
{
    __shared__ float h_lds[RPB][HSTR];
    __shared__ float x_lds[RPB][XSTR];

    const int tid = threadIdx.x;
    const int r   = tid >> 4;      // row within block, 0..15
    const int g   = tid & 15;      // lane group, 0..15
    const int row = blockIdx.x * RPB + r;
    const int jb  = 16 * g;        // hidden-col base (16 cols per lane)
    const int jb3 = 8 * g;         // layer-3 col base (8 cols per lane)

    float* hrow = h_lds[r];
    float* xrow = x_lds[r];

    // ---- stage x_init + t into LDS ----
    #pragma unroll
    for (int i = 0; i < 9; ++i) {
        int j = g + 16 * i;
        if (j < AD) xrow[j] = x_init[(size_t)row * AD + j];
    }
    if (g == 15) xrow[129] = (float)(NSTEP - 1);   // t for step 0
    // ---- stage state into h_lds (input of the pre pass) ----
    {
        const float4* s4 = (const float4*)(state + (size_t)row * SD + jb);
        #pragma unroll
        for (int q = 0; q < 4; ++q) ((float4*)(hrow + jb))[q] = s4[q];
    }

    float pre[16], acc[16];
    {
        const float4* b14 = (const float4*)(b1 + jb);
        #pragma unroll
        for (int q = 0; q < 4; ++q) ((float4*)pre)[q] = b14[q];
    }
    __syncthreads();

    // ---- pre = b1 + state @ W1[0:256,:]  (step-invariant) ----
    mac16(W1 + jb, HID, hrow, SD, pre);

    const float* W1xt = W1 + (size_t)SD * HID;   // rows 256..385 = [x;t] part

    // LayerNorm + ReLU over this row's 256 accs (16 lanes x 16) -> h_lds
    auto ln_relu_store = [&](const float* __restrict__ gamma,
                             const float* __restrict__ beta) {
        float ssum = 0.f;
        #pragma unroll
        for (int j = 0; j < 16; ++j) ssum += acc[j];
        ssum += __shfl_xor(ssum, 1);
        ssum += __shfl_xor(ssum, 2);
        ssum += __shfl_xor(ssum, 4);
        ssum += __shfl_xor(ssum, 8);
        float mean = ssum * (1.0f / 256.0f);
        float vsum = 0.f;
        #pragma unroll
        for (int j = 0; j < 16; ++j) { float d = acc[j] - mean; vsum = fmaf(d, d, vsum); }
        vsum += __shfl_xor(vsum, 1);
        vsum += __shfl_xor(vsum, 2);
        vsum += __shfl_xor(vsum, 4);
        vsum += __shfl_xor(vsum, 8);
        float rs = rsqrtf(vsum * (1.0f / 256.0f) + EPS_LN);
        const float4* g4 = (const float4*)(gamma + jb);
        const float4* b4 = (const float4*)(beta + jb);
        #pragma unroll
        for (int q = 0; q < 4; ++q) {
            float4 gv = g4[q], bv = b4[q];
            float4 h;
            h.x = fmaxf((acc[4*q+0] - mean) * rs * gv.x + bv.x, 0.f);
            h.y = fmaxf((acc[4*q+1] - mean) * rs * gv.y + bv.y, 0.f);
            h.z = fmaxf((acc[4*q+2] - mean) * rs * gv.z + bv.z, 0.f);
            h.w = fmaxf((acc[4*q+3] - mean) * rs * gv.w + bv.w, 0.f);
            ((float4*)(hrow + jb))[q] = h;
        }
    };

    for (int s = 0; s < NSTEP; ++s) {
        // ---- layer 1: acc = pre + [x;t] @ W1[256:386,:]  (K=130) ----
        #pragma unroll
        for (int j = 0; j < 16; ++j) acc[j] = pre[j];
        mac16(W1xt + jb, HID, xrow, 130, acc);
        ln_relu_store(g1, be1);          // prev-step h readers done (end-of-step barrier)
        __syncthreads();                 // h1 visible

        // ---- layer 2: acc = b2 + h1 @ W2 ----
        {
            const float4* b24 = (const float4*)(b2 + jb);
            #pragma unroll
            for (int q = 0; q < 4; ++q) ((float4*)acc)[q] = b24[q];
        }
        mac16(W2 + jb, HID, hrow, HID, acc);
        __syncthreads();                 // h1 reads done before overwrite
        ln_relu_store(g2, be2);
        __syncthreads();                 // h2 visible

        // ---- layer 3: noise_pred; lane owns cols 8g..8g+7, col 128 split over k ----
        float a3[8];
        #pragma unroll
        for (int i = 0; i < 8; ++i) a3[i] = b3[jb3 + i];
        mac8(W3p + jb3, W3STR, hrow, HID, a3);
        // col 128: each lane sums k in [16g, 16g+16)
        float c128 = 0.f;
        #pragma unroll 4
        for (int i = 0; i < 16; ++i) {
            int k = 16 * g + i;
            c128 = fmaf(hrow[k], W3p[k * W3STR + 128], c128);
        }
        c128 += __shfl_xor(c128, 1);
        c128 += __shfl_xor(c128, 2);
        c128 += __shfl_xor(c128, 4);
        c128 += __shfl_xor(c128, 8);

        // ---- x -= 0.1 * noise_pred; set t for next step ----
        #pragma unroll
        for (int i = 0; i < 8; ++i) {
            int j = jb3 + i;
            xrow[j] = xrow[j] - 0.1f * a3[i];
        }
        if (g == 15) {
            xrow[128] = xrow[128] - 0.1f * (c128 + b3[128]);
            xrow[129] = (float)(NSTEP - 2 - s);   // t for next step (unused on last)
        }
        __syncthreads();                 // x (and h-overwrite ordering) for next step
    }

    // ---- finale: masked gumbel softmax -> one-hot (straight-through), tanh(step) ----
    {
        const float4* m4 = (const float4*)(amask + (size_t)row * 128 + jb3);
        const float4* g4 = (const float4*)(gum   + (size_t)row * 128 + jb3);
        float lg[8];
        #pragma unroll
        for (int q = 0; q < 2; ++q) {
            float4 mv = m4[q], gv = g4[q];
            lg[4*q+0] = xrow[jb3+4*q+0] + (1.f - mv.x) * (-1e9f) + gv.x;
            lg[4*q+1] = xrow[jb3+4*q+1] + (1.f - mv.y) * (-1e9f) + gv.y;
            lg[4*q+2] = xrow[jb3+4*q+2] + (1.f - mv.z) * (-1e9f) + gv.z;
            lg[4*q+3] = xrow[jb3+4*q+3] + (1.f - mv.w) * (-1e9f) + gv.w;
        }
        float lmax = lg[0];
        #pragma unroll
        for (int i = 1; i < 8; ++i) lmax = fmaxf(lmax, lg[i]);
        lmax = fmaxf(lmax, __shfl_xor(lmax, 1));
        lmax = fmaxf(lmax, __shfl_xor(lmax, 2));
        lmax = fmaxf(lmax, __shfl_xor(lmax, 4));
        lmax = fmaxf(lmax, __shfl_xor(lmax, 8));
        float es[8];
        float esum = 0.f;
        #pragma unroll
        for (int i = 0; i < 8; ++i) { es[i] = expf(lg[i] - lmax); esum += es[i]; }
        esum += __shfl_xor(esum, 1);
        esum += __shfl_xor(esum, 2);
        esum += __shfl_xor(esum, 4);
        esum += __shfl_xor(esum, 8);
        float soft[8];
        float smax = 0.f;
        #pragma unroll
        for (int i = 0; i < 8; ++i) { soft[i] = es[i] / esum; smax = fmaxf(smax, soft[i]); }
        smax = fmaxf(smax, __shfl_xor(smax, 1));
        smax = fmaxf(smax, __shfl_xor(smax, 2));
        smax = fmaxf(smax, __shfl_xor(smax, 4));
        smax = fmaxf(smax, __shfl_xor(smax, 8));
        int lidx = 0x7fffffff;
        #pragma unroll
        for (int i = 0; i < 8; ++i) {
            if (soft[i] == smax && lidx == 0x7fffffff) lidx = jb3 + i;
        }
        lidx = min(lidx, __shfl_xor(lidx, 1));
        lidx = min(lidx, __shfl_xor(lidx, 2));
        lidx = min(lidx, __shfl_xor(lidx, 4));
        lidx = min(lidx, __shfl_xor(lidx, 8));
        float* orow = out + (size_t)row * AD;
        #pragma unroll
        for (int i = 0; i < 8; ++i) {
            int j = jb3 + i;
            float hard = (j == lidx) ? 1.0f : 0.0f;
            orow[j] = hard + soft[i] - soft[i];
        }
        if (g == 15) orow[128] = tanhf(xrow[128]);
    }
}

extern "C" void kernel_launch(void* const* d_in, const int* in_sizes, int n_in,
                              void* d_out, int out_size, void* d_ws, size_t ws_size,
                              hipStream_t stream) {
    const float* state  = (const float*)d_in[0];
    const float* amask  = (const float*)d_in[1];
    const float* x_init = (const float*)d_in[2];
    const float* gum    = (const float*)d_in[3];
    const float* W1     = (const float*)d_in[4];
    const float* b1     = (const float*)d_in[5];
    const float* g1     = (const float*)d_in[6];
    const float* be1    = (const float*)d_in[7];
    const float* W2     = (const float*)d_in[8];
    const float* b2     = (const float*)d_in[9];
    const float* g2     = (const float*)d_in[10];
    const float* be2    = (const float*)d_in[11];
    const float* W3     = (const float*)d_in[12];
    const float* b3     = (const float*)d_in[13];
    float* out = (float*)d_out;
    float* W3p = (float*)d_ws;    // 256*132*4 = 135168 bytes

    hipLaunchKernelGGL(repack_w3, dim3((HID * W3STR + 255) / 256), dim3(256), 0, stream,
                       W3, W3p);
    hipLaunchKernelGGL(actor_kernel, dim3(BATCH / RPB), dim3(256), 0, stream,
                       state, amask, x_init, gum, W1, b1, g1, be1,
                       W2, b2, g2, be2, W3p, b3, out);
}

// Round 3
// 7994.376 us; speedup vs baseline: 30.4206x; 30.4206x over previous
//
#include <hip/hip_runtime.h>
#include <math.h>

#define BATCH  65536
#define SD     256      // STATE_DIM
#define AD     129      // ACTION_DIM
#define HID    256
#define NSTEP  30
#define EPS_LN 1e-5f

#define M      32       // batch rows per block (wave w owns rows 8w..8w+7)
#define KT     8        // weight k-tile (double-buffered in LDS)

// d_ws layout (dwords): W3 repacked for aligned vector loads
#define WS_W3M  0        // [256][128]  cols 0..127
#define WS_W3C  32768    // [256]       col 128
// total 33024 dw = 132096 B

__global__ __launch_bounds__(256)
void repack_w3(const float* __restrict__ W3, float* __restrict__ ws) {
    int idx = blockIdx.x * 256 + threadIdx.x;
    if (idx < 32768) {
        int k = idx >> 7, j = idx & 127;
        ws[WS_W3M + idx] = W3[k * AD + j];
    } else if (idx < 33024) {
        int k = idx - 32768;
        ws[WS_W3C + k] = W3[k * AD + 128];
    }
}

__device__ __forceinline__ float4 ldf4(const float* p) { return *(const float4*)p; }

__device__ __forceinline__ void wave_reduce_add8(float v[8]) {
    #pragma unroll
    for (int d = 1; d < 64; d <<= 1) {
        #pragma unroll
        for (int r = 0; r < 8; ++r) v[r] += __shfl_xor(v[r], d);
    }
}
__device__ __forceinline__ void wave_reduce_max8(float v[8]) {
    #pragma unroll
    for (int d = 1; d < 64; d <<= 1) {
        #pragma unroll
        for (int r = 0; r < 8; ++r) v[r] = fmaxf(v[r], __shfl_xor(v[r], d));
    }
}
__device__ __forceinline__ void wave_reduce_min8i(int v[8]) {
    #pragma unroll
    for (int d = 1; d < 64; d <<= 1) {
        #pragma unroll
        for (int r = 0; r < 8; ++r) v[r] = min(v[r], __shfl_xor(v[r], d));
    }
}

// acc[r*4+c] += a(row r) * w(col c)
#define FMAROW(AV, R, WV, ACC)                                   \
    ACC[(R)*4+0] = fmaf((AV), (WV).x, ACC[(R)*4+0]);             \
    ACC[(R)*4+1] = fmaf((AV), (WV).y, ACC[(R)*4+1]);             \
    ACC[(R)*4+2] = fmaf((AV), (WV).z, ACC[(R)*4+2]);             \
    ACC[(R)*4+3] = fmaf((AV), (WV).w, ACC[(R)*4+3]);
#define FMAROW2(AV, R, WV, ACC)                                  \
    ACC[(R)*2+0] = fmaf((AV), (WV).x, ACC[(R)*2+0]);             \
    ACC[(R)*2+1] = fmaf((AV), (WV).y, ACC[(R)*2+1]);

__global__ __launch_bounds__(256, 2)
void actor_kernel(const float* __restrict__ state,
                  const float* __restrict__ amask,
                  const float* __restrict__ x_init,
                  const float* __restrict__ gum,
                  const float* __restrict__ W1,
                  const float* __restrict__ b1,
                  const float* __restrict__ g1,
                  const float* __restrict__ be1,
                  const float* __restrict__ W2,
                  const float* __restrict__ b2,
                  const float* __restrict__ g2,
                  const float* __restrict__ be2,
                  const float* __restrict__ ws,
                  const float* __restrict__ b3,
                  float* __restrict__ out)
{
    // Activations transposed: [k][m], m contiguous -> wave-uniform broadcast b128 reads.
    __shared__ __align__(16) float hT[256][36];     // 36.9 KB
    __shared__ __align__(16) float xT[136][36];     // 19.6 KB ([129]=t, 130..135 zero)
    __shared__ __align__(16) float Wt[2][KT][260];  // 16.6 KB (double-buffered k-tile)
    __shared__ __align__(16) float w3c[256];        //  1.0 KB (W3 col 128)

    const int tid   = threadIdx.x;
    const int wv    = tid >> 6;        // wave 0..3: owns rows 8wv..8wv+7
    const int ln    = tid & 63;        // lane: owns cols 4ln..4ln+3 (N=256), 2ln..2ln+1 (N=128)
    const int mbase = 8 * wv;
    const int row0  = blockIdx.x * M;

    const float* W3m = ws + WS_W3M;    // [256][128]

    // ---------------- init staging ----------------
    {   // state -> hT (transposed); 2-way bank aliasing only (free)
        int m = tid & 31, kb = (tid >> 5) * 32;
        const float* sp = state + (size_t)(row0 + m) * SD + kb;
        #pragma unroll
        for (int q = 0; q < 8; ++q) {
            float4 vv = ldf4(sp + 4 * q);
            hT[kb + 4*q + 0][m] = vv.x;
            hT[kb + 4*q + 1][m] = vv.y;
            hT[kb + 4*q + 2][m] = vv.z;
            hT[kb + 4*q + 3][m] = vv.w;
        }
    }
    {   // x_init -> xT, plus t at [129], zeros at [130..135]
        int m = tid & 31, i = tid >> 5;
        #pragma unroll
        for (int q = 0; q < 17; ++q) {
            int k = i + 8 * q;                         // 0..135
            float val;
            if (k < AD)      val = x_init[(size_t)(row0 + m) * AD + k];
            else if (k == AD) val = (float)(NSTEP - 1); // t for step 0 (slot 129)
            else              val = 0.f;
            xT[k][m] = val;
        }
    }
    w3c[tid] = ws[WS_W3C + tid];
    __syncthreads();

    // per-lane constants
    const float4 b1v  = ldf4(b1  + 4 * ln);
    const float4 b2v  = ldf4(b2  + 4 * ln);
    const float4 g1v  = ldf4(g1  + 4 * ln);
    const float4 be1v = ldf4(be1 + 4 * ln);
    const float4 g2v  = ldf4(g2  + 4 * ln);
    const float4 be2v = ldf4(be2 + 4 * ln);
    const float2 b3v  = *(const float2*)(b3 + 2 * ln);
    const float  b3c  = b3[128];

    // ---------------- GEMM engines ----------------
    // N=256: acc[32] (8 rows x 4 cols). Weight tile staged global->LDS, double-buffered,
    // one barrier per tile. kmax masks out-of-range W rows (reads would be OOB).
    auto gemm256 = [&](const float* __restrict__ Wg, int ntiles, int kmax,
                       const float (* __restrict__ aT)[36], float* __restrict__ acc) {
        const int kk = tid >> 5, jj = (tid & 31) * 8;
        {
            const float* s = Wg + (size_t)kk * HID + jj;   // rows 0..7 < kmax always
            float4 r0 = ldf4(s), r1 = ldf4(s + 4);
            *(float4*)&Wt[0][kk][jj]     = r0;
            *(float4*)&Wt[0][kk][jj + 4] = r1;
        }
        __syncthreads();
        int buf = 0;
        #pragma unroll 1
        for (int t = 0; t < ntiles; ++t) {
            float4 r0 = {0,0,0,0}, r1 = {0,0,0,0};
            const bool more = (t + 1 < ntiles);
            if (more) {
                int krow = (t + 1) * KT + kk;
                if (krow < kmax) {
                    const float* s = Wg + (size_t)krow * HID + jj;
                    r0 = ldf4(s); r1 = ldf4(s + 4);
                }
            }
            #pragma unroll
            for (int kq = 0; kq < KT; ++kq) {
                const int k = t * KT + kq;
                float4 a0 = *(const float4*)&aT[k][mbase];      // broadcast
                float4 a1 = *(const float4*)&aT[k][mbase + 4];  // broadcast
                float4 w  = *(const float4*)&Wt[buf][kq][4 * ln];
                FMAROW(a0.x, 0, w, acc) FMAROW(a0.y, 1, w, acc)
                FMAROW(a0.z, 2, w, acc) FMAROW(a0.w, 3, w, acc)
                FMAROW(a1.x, 4, w, acc) FMAROW(a1.y, 5, w, acc)
                FMAROW(a1.z, 6, w, acc) FMAROW(a1.w, 7, w, acc)
            }
            if (more) {
                *(float4*)&Wt[buf ^ 1][kk][jj]     = r0;
                *(float4*)&Wt[buf ^ 1][kk][jj + 4] = r1;
            }
            __syncthreads();
            buf ^= 1;
        }
    };
    // N=128 (layer 3 cols 0..127): acc[16] (8 rows x 2 cols)
    auto gemm128 = [&](const float* __restrict__ Wg, int ntiles, float* __restrict__ acc) {
        const int kk = tid >> 5, jj = (tid & 31) * 4;
        {
            float4 r0 = ldf4(Wg + (size_t)kk * 128 + jj);
            *(float4*)&Wt[0][kk][jj] = r0;
        }
        __syncthreads();
        int buf = 0;
        #pragma unroll 1
        for (int t = 0; t < ntiles; ++t) {
            float4 r0 = {0,0,0,0};
            const bool more = (t + 1 < ntiles);
            if (more) r0 = ldf4(Wg + (size_t)((t + 1) * KT + kk) * 128 + jj);
            #pragma unroll
            for (int kq = 0; kq < KT; ++kq) {
                const int k = t * KT + kq;
                float4 a0 = *(const float4*)&hT[k][mbase];
                float4 a1 = *(const float4*)&hT[k][mbase + 4];
                float2 w  = *(const float2*)&Wt[buf][kq][2 * ln];
                FMAROW2(a0.x, 0, w, acc) FMAROW2(a0.y, 1, w, acc)
                FMAROW2(a0.z, 2, w, acc) FMAROW2(a0.w, 3, w, acc)
                FMAROW2(a1.x, 4, w, acc) FMAROW2(a1.y, 5, w, acc)
                FMAROW2(a1.z, 6, w, acc) FMAROW2(a1.w, 7, w, acc)
            }
            if (more) *(float4*)&Wt[buf ^ 1][kk][jj] = r0;
            __syncthreads();
            buf ^= 1;
        }
    };

    // LayerNorm + ReLU on acc[32] (8 rows across the wave's 64 lanes x 4 cols),
    // transposed store into hT. Rows are wave-private.
    auto ln_relu = [&](float* __restrict__ acc, float4 gv, float4 bv) {
        float s[8];
        #pragma unroll
        for (int r = 0; r < 8; ++r)
            s[r] = (acc[4*r] + acc[4*r+1]) + (acc[4*r+2] + acc[4*r+3]);
        wave_reduce_add8(s);
        float mean[8];
        #pragma unroll
        for (int r = 0; r < 8; ++r) mean[r] = s[r] * (1.f / 256.f);
        float v[8];
        #pragma unroll
        for (int r = 0; r < 8; ++r) {
            float d0 = acc[4*r]   - mean[r], d1 = acc[4*r+1] - mean[r];
            float d2 = acc[4*r+2] - mean[r], d3 = acc[4*r+3] - mean[r];
            v[r] = fmaf(d0, d0, fmaf(d1, d1, fmaf(d2, d2, d3 * d3)));
        }
        wave_reduce_add8(v);
        float rs[8];
        #pragma unroll
        for (int r = 0; r < 8; ++r) rs[r] = rsqrtf(fmaf(v[r], 1.f / 256.f, EPS_LN));
        const float ga[4] = {gv.x, gv.y, gv.z, gv.w};
        const float ba[4] = {bv.x, bv.y, bv.z, bv.w};
        #pragma unroll
        for (int c = 0; c < 4; ++c) {
            float4 lo, hi;
            lo.x = fmaxf(fmaf((acc[0*4+c] - mean[0]) * rs[0], ga[c], ba[c]), 0.f);
            lo.y = fmaxf(fmaf((acc[1*4+c] - mean[1]) * rs[1], ga[c], ba[c]), 0.f);
            lo.z = fmaxf(fmaf((acc[2*4+c] - mean[2]) * rs[2], ga[c], ba[c]), 0.f);
            lo.w = fmaxf(fmaf((acc[3*4+c] - mean[3]) * rs[3], ga[c], ba[c]), 0.f);
            hi.x = fmaxf(fmaf((acc[4*4+c] - mean[4]) * rs[4], ga[c], ba[c]), 0.f);
            hi.y = fmaxf(fmaf((acc[5*4+c] - mean[5]) * rs[5], ga[c], ba[c]), 0.f);
            hi.z = fmaxf(fmaf((acc[6*4+c] - mean[6]) * rs[6], ga[c], ba[c]), 0.f);
            hi.w = fmaxf(fmaf((acc[7*4+c] - mean[7]) * rs[7], ga[c], ba[c]), 0.f);
            *(float4*)&hT[4*ln + c][mbase]     = lo;
            *(float4*)&hT[4*ln + c][mbase + 4] = hi;
        }
    };

    // ---------------- pre = b1 + state @ W1[0:256,:] (step-invariant) ----------------
    float pre[32];
    #pragma unroll
    for (int r = 0; r < 8; ++r) {
        pre[4*r+0] = b1v.x; pre[4*r+1] = b1v.y; pre[4*r+2] = b1v.z; pre[4*r+3] = b1v.w;
    }
    gemm256(W1, 32, 256, hT, pre);

    const float* W1x = W1 + (size_t)SD * HID;   // rows 256..385 ([x;t]), 130 valid rows

    // ---------------- diffusion steps ----------------
    float acc[32];
    #pragma unroll 1
    for (int s = 0; s < NSTEP; ++s) {
        // layer 1: acc = pre + [x;t] @ W1x   (K=136 padded, rows >=130 masked to 0)
        #pragma unroll
        for (int j = 0; j < 32; ++j) acc[j] = pre[j];
        gemm256(W1x, 17, 130, xT, acc);
        ln_relu(acc, g1v, be1v);
        __syncthreads();

        // layer 2: acc = b2 + h1 @ W2
        #pragma unroll
        for (int r = 0; r < 8; ++r) {
            acc[4*r+0] = b2v.x; acc[4*r+1] = b2v.y; acc[4*r+2] = b2v.z; acc[4*r+3] = b2v.w;
        }
        gemm256(W2, 32, 256, hT, acc);
        ln_relu(acc, g2v, be2v);
        __syncthreads();

        // layer 3 cols 0..127: a3 = b3 + h2 @ W3m
        float a3[16];
        #pragma unroll
        for (int r = 0; r < 8; ++r) { a3[2*r] = b3v.x; a3[2*r+1] = b3v.y; }
        gemm128(W3m, 32, a3);

        // col 128 via whole-wave k-split reduction
        float c1[8];
        #pragma unroll
        for (int r = 0; r < 8; ++r) c1[r] = 0.f;
        #pragma unroll
        for (int q = 0; q < 4; ++q) {
            int k = ln + 64 * q;
            float wc = w3c[k];
            float4 h0 = *(const float4*)&hT[k][mbase];
            float4 h1 = *(const float4*)&hT[k][mbase + 4];
            c1[0] = fmaf(h0.x, wc, c1[0]); c1[1] = fmaf(h0.y, wc, c1[1]);
            c1[2] = fmaf(h0.z, wc, c1[2]); c1[3] = fmaf(h0.w, wc, c1[3]);
            c1[4] = fmaf(h1.x, wc, c1[4]); c1[5] = fmaf(h1.y, wc, c1[5]);
            c1[6] = fmaf(h1.z, wc, c1[6]); c1[7] = fmaf(h1.w, wc, c1[7]);
        }
        wave_reduce_add8(c1);

        // x -= 0.1 * noise_pred (wave-private rows)
        #pragma unroll
        for (int c = 0; c < 2; ++c) {
            int col = 2 * ln + c;
            float4 lo = *(const float4*)&xT[col][mbase];
            float4 hi = *(const float4*)&xT[col][mbase + 4];
            lo.x -= 0.1f * a3[0*2+c]; lo.y -= 0.1f * a3[1*2+c];
            lo.z -= 0.1f * a3[2*2+c]; lo.w -= 0.1f * a3[3*2+c];
            hi.x -= 0.1f * a3[4*2+c]; hi.y -= 0.1f * a3[5*2+c];
            hi.z -= 0.1f * a3[6*2+c]; hi.w -= 0.1f * a3[7*2+c];
            *(float4*)&xT[col][mbase]     = lo;
            *(float4*)&xT[col][mbase + 4] = hi;
        }
        if (ln == 0) {
            float4 lo = *(const float4*)&xT[128][mbase];
            float4 hi = *(const float4*)&xT[128][mbase + 4];
            lo.x -= 0.1f * (c1[0] + b3c); lo.y -= 0.1f * (c1[1] + b3c);
            lo.z -= 0.1f * (c1[2] + b3c); lo.w -= 0.1f * (c1[3] + b3c);
            hi.x -= 0.1f * (c1[4] + b3c); hi.y -= 0.1f * (c1[5] + b3c);
            hi.z -= 0.1f * (c1[6] + b3c); hi.w -= 0.1f * (c1[7] + b3c);
            *(float4*)&xT[128][mbase]     = lo;
            *(float4*)&xT[128][mbase + 4] = hi;
        }
        if (ln == 1) {
            float tn = (float)(NSTEP - 2 - s);
            float4 tv = {tn, tn, tn, tn};
            *(float4*)&xT[129][mbase]     = tv;
            *(float4*)&xT[129][mbase + 4] = tv;
        }
        __syncthreads();
    }

    // ---------------- finale ----------------
    {
        float xv[16];
        #pragma unroll
        for (int c = 0; c < 2; ++c) {
            int col = 2 * ln + c;
            float4 lo = *(const float4*)&xT[col][mbase];
            float4 hi = *(const float4*)&xT[col][mbase + 4];
            xv[0*2+c] = lo.x; xv[1*2+c] = lo.y; xv[2*2+c] = lo.z; xv[3*2+c] = lo.w;
            xv[4*2+c] = hi.x; xv[5*2+c] = hi.y; xv[6*2+c] = hi.z; xv[7*2+c] = hi.w;
        }
        float lg[16];
        #pragma unroll
        for (int r = 0; r < 8; ++r) {
            size_t grow = (size_t)(row0 + mbase + r);
            float2 mv = *(const float2*)&amask[grow * 128 + 2 * ln];
            float2 gv = *(const float2*)&gum  [grow * 128 + 2 * ln];
            lg[r*2+0] = xv[r*2+0] + (1.f - mv.x) * -1e9f + gv.x;
            lg[r*2+1] = xv[r*2+1] + (1.f - mv.y) * -1e9f + gv.y;
        }
        float mx[8];
        #pragma unroll
        for (int r = 0; r < 8; ++r) mx[r] = fmaxf(lg[r*2], lg[r*2+1]);
        wave_reduce_max8(mx);
        float es[16], sum[8];
        #pragma unroll
        for (int r = 0; r < 8; ++r) {
            es[r*2+0] = expf(lg[r*2+0] - mx[r]);
            es[r*2+1] = expf(lg[r*2+1] - mx[r]);
            sum[r] = es[r*2+0] + es[r*2+1];
        }
        wave_reduce_add8(sum);
        float soft[16], sm[8];
        #pragma unroll
        for (int r = 0; r < 8; ++r) {
            soft[r*2+0] = es[r*2+0] / sum[r];
            soft[r*2+1] = es[r*2+1] / sum[r];
            sm[r] = fmaxf(soft[r*2+0], soft[r*2+1]);
        }
        wave_reduce_max8(sm);
        int idx[8];
        #pragma unroll
        for (int r = 0; r < 8; ++r) {
            idx[r] = (soft[r*2+0] == sm[r]) ? (2*ln)
                   : ((soft[r*2+1] == sm[r]) ? (2*ln + 1) : 0x7fffffff);
        }
        wave_reduce_min8i(idx);
        #pragma unroll
        for (int r = 0; r < 8; ++r) {
            size_t grow = (size_t)(row0 + mbase + r);
            float* orow = out + grow * AD;
            float h0 = (2*ln + 0 == idx[r]) ? 1.f : 0.f;
            float h1 = (2*ln + 1 == idx[r]) ? 1.f : 0.f;
            orow[2*ln+0] = h0 + soft[r*2+0] - soft[r*2+0];
            orow[2*ln+1] = h1 + soft[r*2+1] - soft[r*2+1];
        }
        if (ln == 0) {
            float4 lo = *(const float4*)&xT[128][mbase];
            float4 hi = *(const float4*)&xT[128][mbase + 4];
            float sv[8] = {lo.x, lo.y, lo.z, lo.w, hi.x, hi.y, hi.z, hi.w};
            #pragma unroll
            for (int r = 0; r < 8; ++r)
                out[(size_t)(row0 + mbase + r) * AD + 128] = tanhf(sv[r]);
        }
    }
}

extern "C" void kernel_launch(void* const* d_in, const int* in_sizes, int n_in,
                              void* d_out, int out_size, void* d_ws, size_t ws_size,
                              hipStream_t stream) {
    const float* state  = (const float*)d_in[0];
    const float* amask  = (const float*)d_in[1];
    const float* x_init = (const float*)d_in[2];
    const float* gum    = (const float*)d_in[3];
    const float* W1     = (const float*)d_in[4];
    const float* b1     = (const float*)d_in[5];
    const float* g1     = (const float*)d_in[6];
    const float* be1    = (const float*)d_in[7];
    const float* W2     = (const float*)d_in[8];
    const float* b2     = (const float*)d_in[9];
    const float* g2     = (const float*)d_in[10];
    const float* be2    = (const float*)d_in[11];
    const float* W3     = (const float*)d_in[12];
    const float* b3     = (const float*)d_in[13];
    float* out = (float*)d_out;
    float* ws  = (float*)d_ws;   // 132096 B used

    hipLaunchKernelGGL(repack_w3, dim3(129), dim3(256), 0, stream, W3, ws);
    hipLaunchKernelGGL(actor_kernel, dim3(BATCH / M), dim3(256), 0, stream,
                       state, amask, x_init, gum, W1, b1, g1, be1,
                       W2, b2, g2, be2, ws, b3, out);
}